// Round 2
// baseline (126.426 us; speedup 1.0000x reference)
//
#include <hip/hip_runtime.h>
#include <math.h>

#define BS   16
#define PP   2048
#define CIN  500
#define NROW (BS * PP)          // 32768
#define ITILES 32               // 64-row i-tiles per batch
#define NBLK_MAIN (BS * ITILES) // 512

// ---------------------------------------------------------------------------
// K1: xr_k = softmax(inputs @ fc_w^T + fc_b) per row of 4.
// One wave per row; fc_w staged to LDS as float4 per k (w for the 4 classes).
// ---------------------------------------------------------------------------
__global__ void __launch_bounds__(256) fc_softmax_kernel(
    const float* __restrict__ inputs, const float* __restrict__ fc_w,
    const float* __restrict__ fc_b, float* __restrict__ out)
{
    __shared__ float4 wL[CIN];
    int tid = threadIdx.x;
    for (int k = tid; k < CIN; k += 256)
        wL[k] = make_float4(fc_w[k], fc_w[CIN + k], fc_w[2 * CIN + k], fc_w[3 * CIN + k]);
    __syncthreads();

    int lane = tid & 63;
    int row  = blockIdx.x * 4 + (tid >> 6);
    const float4* in4 = (const float4*)(inputs + (size_t)row * CIN);

    float a0 = 0.f, a1 = 0.f, a2 = 0.f, a3 = 0.f;
#pragma unroll
    for (int t = 0; t < 2; ++t) {
        int f = t * 64 + lane;          // 125 float4 per row
        if (f < 125) {
            float4 x = in4[f];
            float4 w0 = wL[f * 4 + 0], w1 = wL[f * 4 + 1];
            float4 w2 = wL[f * 4 + 2], w3 = wL[f * 4 + 3];
            a0 += x.x * w0.x + x.y * w1.x + x.z * w2.x + x.w * w3.x;
            a1 += x.x * w0.y + x.y * w1.y + x.z * w2.y + x.w * w3.y;
            a2 += x.x * w0.z + x.y * w1.z + x.z * w2.z + x.w * w3.z;
            a3 += x.x * w0.w + x.y * w1.w + x.z * w2.w + x.w * w3.w;
        }
    }
#pragma unroll
    for (int off = 32; off > 0; off >>= 1) {
        a0 += __shfl_xor(a0, off);
        a1 += __shfl_xor(a1, off);
        a2 += __shfl_xor(a2, off);
        a3 += __shfl_xor(a3, off);
    }
    if (lane == 0) {
        a0 += fc_b[0]; a1 += fc_b[1]; a2 += fc_b[2]; a3 += fc_b[3];
        float m = fmaxf(fmaxf(a0, a1), fmaxf(a2, a3));
        float e0 = expf(a0 - m), e1 = expf(a1 - m), e2 = expf(a2 - m), e3 = expf(a3 - m);
        float inv = 1.0f / (e0 + e1 + e2 + e3);
        ((float4*)out)[row] = make_float4(e0 * inv, e1 * inv, e2 * inv, e3 * inv);
    }
}

// ---------------------------------------------------------------------------
// K2: candidate masks per (b, c): cand = pre_score > 0.5, fallback to one-hot
// argmax (first-max tie-break) when count <= 1. Packed 3 bits per (b, j).
// ---------------------------------------------------------------------------
__global__ void __launch_bounds__(256) cand_kernel(
    const float* __restrict__ pre_score, unsigned char* __restrict__ packed)
{
    int b = blockIdx.x;
    int tid = threadIdx.x;
    __shared__ float sv[256];
    __shared__ int   si[256];
    __shared__ int   sc[256];

    unsigned char bits[8];
    float myv[8];
#pragma unroll
    for (int t = 0; t < 8; ++t) bits[t] = 0;

    for (int c = 0; c < 3; ++c) {
        float bv = -1.0f; int bi = 0; int cnt = 0;
#pragma unroll
        for (int t = 0; t < 8; ++t) {
            int j = t * 256 + tid;      // ascending j per thread
            float v = pre_score[((size_t)b * PP + j) * 3 + c];
            myv[t] = v;
            if (v > 0.5f) cnt++;
            if (v > bv) { bv = v; bi = j; }   // strict > => first max
        }
        sv[tid] = bv; si[tid] = bi; sc[tid] = cnt;
        __syncthreads();
        for (int s2 = 128; s2 > 0; s2 >>= 1) {
            if (tid < s2) {
                float ov = sv[tid + s2]; int oi = si[tid + s2];
                if (ov > sv[tid] || (ov == sv[tid] && oi < si[tid])) { sv[tid] = ov; si[tid] = oi; }
                sc[tid] += sc[tid + s2];
            }
            __syncthreads();
        }
        int total = sc[0];
        int amax  = si[0];
        __syncthreads();   // everyone has read [0] before next class reuses LDS
#pragma unroll
        for (int t = 0; t < 8; ++t) {
            int j = t * 256 + tid;
            bool cb = (total <= 1) ? (j == amax) : (myv[t] > 0.5f);
            if (cb) bits[t] |= (unsigned char)(1 << c);
        }
    }
#pragma unroll
    for (int t = 0; t < 8; ++t)
        packed[(size_t)b * PP + t * 256 + tid] = bits[t];
}

// ---------------------------------------------------------------------------
// K3: main — per (b, i): masked IoU argmax per class, sequential class logic,
// focal loss; per-block partial sums of w and floss.
// Block = 256 threads = 4 waves; block covers one batch b and 64 i's.
// Wave s scans j in [512s, 512s+512); all 64 lanes share j (LDS broadcast).
// ---------------------------------------------------------------------------
__global__ void __launch_bounds__(256) main_kernel(
    const float* __restrict__ rois, const float* __restrict__ pre_score,
    const int* __restrict__ labels, const unsigned char* __restrict__ packed,
    const float* __restrict__ xr, float* __restrict__ partials)
{
    int b     = blockIdx.x >> 5;     // / ITILES
    int itile = blockIdx.x & 31;

    __shared__ float x1L[PP], y1L[PP], x2L[PP], y2L[PP], aL[PP];
    __shared__ unsigned char cL[PP];
    __shared__ float bestL[3][4][64];
    __shared__ int   jsL[3][4][64];

    int tid = threadIdx.x;
    const float4* rb = (const float4*)(rois + (size_t)b * PP * 4);
    for (int t = tid; t < PP; t += 256) {
        float4 bx = rb[t];
        x1L[t] = bx.x; y1L[t] = bx.y; x2L[t] = bx.z; y2L[t] = bx.w;
        aL[t] = (bx.z - bx.x) * (bx.w - bx.y);
        cL[t] = packed[(size_t)b * PP + t];
    }
    __syncthreads();

    int lane = tid & 63, s = tid >> 6;
    int i = itile * 64 + lane;
    float x1i = x1L[i], y1i = y1L[i], x2i = x2L[i], y2i = y2L[i], ai = aL[i];

    float best0 = -1.f, best1 = -1.f, best2 = -1.f;
    int   j0 = 0, j1 = 0, j2 = 0;
    int jb = s * 512;
    for (int jj = 0; jj < 512; ++jj) {
        int j = jb + jj;
        float lx = fmaxf(x1i, x1L[j]);
        float ly = fmaxf(y1i, y1L[j]);
        float rx = fminf(x2i, x2L[j]);
        float ry = fminf(y2i, y2L[j]);
        float w  = fmaxf(rx - lx, 0.f);
        float h  = fmaxf(ry - ly, 0.f);
        float inter = w * h;
        float uni   = ai + aL[j] - inter;
        float iou   = __fdividef(inter, uni);
        int pk = cL[j];
        if ((pk & 1) && iou > best0) { best0 = iou; j0 = j; }
        if ((pk & 2) && iou > best1) { best1 = iou; j1 = j; }
        if ((pk & 4) && iou > best2) { best2 = iou; j2 = j; }
    }
    bestL[0][s][lane] = best0; jsL[0][s][lane] = j0;
    bestL[1][s][lane] = best1; jsL[1][s][lane] = j1;
    bestL[2][s][lane] = best2; jsL[2][s][lane] = j2;
    __syncthreads();

    if (tid < 64) {
        float bb[3]; int jjx[3];
#pragma unroll
        for (int c = 0; c < 3; ++c) {
            float v = bestL[c][0][lane]; int jv = jsL[c][0][lane];
#pragma unroll
            for (int ss = 1; ss < 4; ++ss) {
                float ov = bestL[c][ss][lane]; int oi = jsL[c][ss][lane];
                if (ov > v || (ov == v && oi < jv)) { v = ov; jv = oi; }
            }
            bb[c] = v; jjx[c] = jv;
        }
        // sequential class assignment (strict >, earlier class wins ties)
        float I = 0.f, wv = 0.f;
        int target = 3;
#pragma unroll
        for (int c = 0; c < 3; ++c) {
            float bestv = (labels[b * 3 + c] != 0) ? bb[c] : -1.0f;
            if (bestv > I) {
                wv = pre_score[((size_t)b * PP + jjx[c]) * 3 + c];
                if (bestv > 0.5f && target == 3) target = c;
                I = bestv;
            }
        }
        // focal loss on double-softmaxed scores
        int gi = b * PP + itile * 64 + lane;
        float4 x4 = ((const float4*)xr)[gi];
        float m = fmaxf(fmaxf(x4.x, x4.y), fmaxf(x4.z, x4.w));
        float e0 = expf(x4.x - m), e1 = expf(x4.y - m), e2 = expf(x4.z - m), e3 = expf(x4.w - m);
        float ssum = e0 + e1 + e2 + e3;
        float et = (target == 0) ? e0 : (target == 1) ? e1 : (target == 2) ? e2 : e3;
        float pt = et / ssum;
        pt = fminf(fmaxf(pt, 1e-7f), 1.0f - 1e-7f);
        float fl = -logf(pt) * (1.0f - pt) * (1.0f - pt);

        float sw = wv, sf = fl;
#pragma unroll
        for (int off = 32; off > 0; off >>= 1) {
            sw += __shfl_down(sw, off);
            sf += __shfl_down(sf, off);
        }
        if (lane == 0) {
            partials[blockIdx.x * 2 + 0] = sw;
            partials[blockIdx.x * 2 + 1] = sf;
        }
    }
}

// ---------------------------------------------------------------------------
// K4: deterministic finalize: loss = mean(w) * mean(floss)
// ---------------------------------------------------------------------------
__global__ void __launch_bounds__(256) finalize_kernel(
    const float* __restrict__ partials, float* __restrict__ out_loss)
{
    __shared__ float swL[256], sfL[256];
    int tid = threadIdx.x;
    float sw = 0.f, sf = 0.f;
    for (int t = tid; t < NBLK_MAIN; t += 256) {
        sw += partials[2 * t];
        sf += partials[2 * t + 1];
    }
    swL[tid] = sw; sfL[tid] = sf;
    __syncthreads();
    for (int s = 128; s > 0; s >>= 1) {
        if (tid < s) { swL[tid] += swL[tid + s]; sfL[tid] += sfL[tid + s]; }
        __syncthreads();
    }
    if (tid == 0)
        out_loss[0] = (swL[0] / (float)NROW) * (sfL[0] / (float)NROW);
}

// ---------------------------------------------------------------------------
extern "C" void kernel_launch(void* const* d_in, const int* in_sizes, int n_in,
                              void* d_out, int out_size, void* d_ws, size_t ws_size,
                              hipStream_t stream)
{
    const float* inputs    = (const float*)d_in[0];
    const float* pre_score = (const float*)d_in[1];
    const int*   labels    = (const int*)d_in[2];     // bool -> int per harness
    const float* rois      = (const float*)d_in[3];
    // d_in[4] = num (2048, fixed)
    const float* fc_w      = (const float*)d_in[5];
    const float* fc_b      = (const float*)d_in[6];

    float* out = (float*)d_out;
    unsigned char* packed  = (unsigned char*)d_ws;
    float* partials        = (float*)((char*)d_ws + (size_t)BS * PP);

    fc_softmax_kernel<<<NROW / 4, 256, 0, stream>>>(inputs, fc_w, fc_b, out);
    cand_kernel<<<BS, 256, 0, stream>>>(pre_score, packed);
    main_kernel<<<NBLK_MAIN, 256, 0, stream>>>(rois, pre_score, labels, packed, out, partials);
    finalize_kernel<<<1, 256, 0, stream>>>(partials, out + (size_t)NROW * 4);
}

// Round 3
// 102.080 us; speedup vs baseline: 1.2385x; 1.2385x over previous
//
#include <hip/hip_runtime.h>
#include <math.h>

#define BS   16
#define PP   2048
#define CIN  500
#define NROW (BS * PP)          // 32768
#define ITILES 32               // 64-row i-tiles per batch
#define NBLK_MAIN (BS * ITILES) // 512

// ---------------------------------------------------------------------------
// K1: xr_k = softmax(inputs @ fc_w^T + fc_b) per row of 4.
// ---------------------------------------------------------------------------
__global__ void __launch_bounds__(256) fc_softmax_kernel(
    const float* __restrict__ inputs, const float* __restrict__ fc_w,
    const float* __restrict__ fc_b, float* __restrict__ out)
{
    __shared__ float4 wL[CIN];
    int tid = threadIdx.x;
    for (int k = tid; k < CIN; k += 256)
        wL[k] = make_float4(fc_w[k], fc_w[CIN + k], fc_w[2 * CIN + k], fc_w[3 * CIN + k]);
    __syncthreads();

    int lane = tid & 63;
    int row  = blockIdx.x * 4 + (tid >> 6);
    const float4* in4 = (const float4*)(inputs + (size_t)row * CIN);

    float a0 = 0.f, a1 = 0.f, a2 = 0.f, a3 = 0.f;
#pragma unroll
    for (int t = 0; t < 2; ++t) {
        int f = t * 64 + lane;          // 125 float4 per row
        if (f < 125) {
            float4 x = in4[f];
            float4 w0 = wL[f * 4 + 0], w1 = wL[f * 4 + 1];
            float4 w2 = wL[f * 4 + 2], w3 = wL[f * 4 + 3];
            a0 += x.x * w0.x + x.y * w1.x + x.z * w2.x + x.w * w3.x;
            a1 += x.x * w0.y + x.y * w1.y + x.z * w2.y + x.w * w3.y;
            a2 += x.x * w0.z + x.y * w1.z + x.z * w2.z + x.w * w3.z;
            a3 += x.x * w0.w + x.y * w1.w + x.z * w2.w + x.w * w3.w;
        }
    }
#pragma unroll
    for (int off = 32; off > 0; off >>= 1) {
        a0 += __shfl_xor(a0, off);
        a1 += __shfl_xor(a1, off);
        a2 += __shfl_xor(a2, off);
        a3 += __shfl_xor(a3, off);
    }
    if (lane == 0) {
        a0 += fc_b[0]; a1 += fc_b[1]; a2 += fc_b[2]; a3 += fc_b[3];
        float m = fmaxf(fmaxf(a0, a1), fmaxf(a2, a3));
        float e0 = expf(a0 - m), e1 = expf(a1 - m), e2 = expf(a2 - m), e3 = expf(a3 - m);
        float inv = 1.0f / (e0 + e1 + e2 + e3);
        ((float4*)out)[row] = make_float4(e0 * inv, e1 * inv, e2 * inv, e3 * inv);
    }
}

// ---------------------------------------------------------------------------
// K2: prep — candidate logic (score>0.5, fallback to first-argmax one-hot when
// count<=1), then pack per-j record: {x1,y1,x2,y2} {area, bias0, bias1, bias2}
// where bias_c = cand ? 0 : -3 (key = iou + bias never wins vs init -1).
// ---------------------------------------------------------------------------
__global__ void __launch_bounds__(256) prep_kernel(
    const float* __restrict__ pre_score, const float* __restrict__ rois,
    float* __restrict__ recs)
{
    int b = blockIdx.x;
    int tid = threadIdx.x;
    __shared__ float sv[256];
    __shared__ int   si[256];
    __shared__ int   sc[256];

    unsigned char bits[8];
    float myv[8];
#pragma unroll
    for (int t = 0; t < 8; ++t) bits[t] = 0;

    for (int c = 0; c < 3; ++c) {
        float bv = -1.0f; int bi = 0; int cnt = 0;
#pragma unroll
        for (int t = 0; t < 8; ++t) {
            int j = t * 256 + tid;      // ascending j per thread
            float v = pre_score[((size_t)b * PP + j) * 3 + c];
            myv[t] = v;
            if (v > 0.5f) cnt++;
            if (v > bv) { bv = v; bi = j; }   // strict > => first max
        }
        sv[tid] = bv; si[tid] = bi; sc[tid] = cnt;
        __syncthreads();
        for (int s2 = 128; s2 > 0; s2 >>= 1) {
            if (tid < s2) {
                float ov = sv[tid + s2]; int oi = si[tid + s2];
                if (ov > sv[tid] || (ov == sv[tid] && oi < si[tid])) { sv[tid] = ov; si[tid] = oi; }
                sc[tid] += sc[tid + s2];
            }
            __syncthreads();
        }
        int total = sc[0];
        int amax  = si[0];
        __syncthreads();
#pragma unroll
        for (int t = 0; t < 8; ++t) {
            int j = t * 256 + tid;
            bool cb = (total <= 1) ? (j == amax) : (myv[t] > 0.5f);
            if (cb) bits[t] |= (unsigned char)(1 << c);
        }
    }

    const float4* rb = (const float4*)(rois + (size_t)b * PP * 4);
    float4* r4 = (float4*)(recs + (size_t)b * PP * 8);
#pragma unroll
    for (int t = 0; t < 8; ++t) {
        int j = t * 256 + tid;
        float4 bx = rb[j];
        float area = (bx.z - bx.x) * (bx.w - bx.y);
        r4[2 * j]     = bx;
        r4[2 * j + 1] = make_float4(area,
                                    (bits[t] & 1) ? 0.f : -3.f,
                                    (bits[t] & 2) ? 0.f : -3.f,
                                    (bits[t] & 4) ? 0.f : -3.f);
    }
}

// ---------------------------------------------------------------------------
// K3: main — block = 512 threads (8 waves) covers 64 i's (one per lane) x all
// 2048 j's; wave w scans j in [256w, 256w+256) (ascending => first-max ties).
// Per-j data broadcast from LDS via 2x ds_read_b128. Combine arrays alias the
// staging LDS after a barrier, keeping the block at exactly 64 KiB.
// ---------------------------------------------------------------------------
__global__ void __launch_bounds__(512) main_kernel(
    const float* __restrict__ recs, const float* __restrict__ pre_score,
    const int* __restrict__ labels, const float* __restrict__ xr,
    float* __restrict__ partials)
{
    __shared__ float recsL[PP * 8];   // 64 KiB
    int b     = blockIdx.x >> 5;
    int itile = blockIdx.x & 31;
    int tid   = threadIdx.x;

    const float4* src = (const float4*)(recs + (size_t)b * PP * 8);
    float4* dstL = (float4*)recsL;
    for (int idx = tid; idx < PP * 2; idx += 512)
        dstL[idx] = src[idx];
    __syncthreads();

    int lane = tid & 63, w = tid >> 6;
    int i = itile * 64 + lane;
    float4 bi = dstL[2 * i];
    float  ai = recsL[8 * i + 4];

    float best0 = -1.f, best1 = -1.f, best2 = -1.f;
    int   j0 = 0, j1 = 0, j2 = 0;
    int jb = w * 256;
#pragma unroll 4
    for (int jj = 0; jj < 256; ++jj) {
        int j = jb + jj;
        float4 bj = dstL[2 * j];
        float4 mj = dstL[2 * j + 1];
        float lx = fmaxf(bi.x, bj.x);
        float ly = fmaxf(bi.y, bj.y);
        float rx = fminf(bi.z, bj.z);
        float ry = fminf(bi.w, bj.w);
        float ww = fmaxf(rx - lx, 0.f);
        float hh = fmaxf(ry - ly, 0.f);
        float inter = ww * hh;
        float uni   = ai + mj.x - inter;
        float iou   = __fdividef(inter, uni);
        float k0 = iou + mj.y;
        float k1 = iou + mj.z;
        float k2 = iou + mj.w;
        if (k0 > best0) { best0 = k0; j0 = j; }
        if (k1 > best1) { best1 = k1; j1 = j; }
        if (k2 > best2) { best2 = k2; j2 = j; }
    }
    __syncthreads();                    // everyone done reading staged recs
    float* bestA = recsL;               // [3][8][64] floats
    int*   jA    = (int*)recsL + 1536;  // [3][8][64] ints
    bestA[(0 * 8 + w) * 64 + lane] = best0; jA[(0 * 8 + w) * 64 + lane] = j0;
    bestA[(1 * 8 + w) * 64 + lane] = best1; jA[(1 * 8 + w) * 64 + lane] = j1;
    bestA[(2 * 8 + w) * 64 + lane] = best2; jA[(2 * 8 + w) * 64 + lane] = j2;
    __syncthreads();

    if (tid < 64) {
        float I = 0.f, wv = 0.f;
        int target = 3;
#pragma unroll
        for (int c = 0; c < 3; ++c) {
            float v = bestA[c * 512 + tid];
            int  jv = jA[c * 512 + tid];
#pragma unroll
            for (int ww2 = 1; ww2 < 8; ++ww2) {
                float ov = bestA[c * 512 + ww2 * 64 + tid];
                int   oi = jA[c * 512 + ww2 * 64 + tid];
                if (ov > v) { v = ov; jv = oi; }   // strict >: earlier wave (smaller j) wins ties
            }
            float bestv = (labels[b * 3 + c] != 0) ? v : -1.0f;
            if (bestv > I) {
                wv = pre_score[((size_t)b * PP + jv) * 3 + c];
                if (bestv > 0.5f && target == 3) target = c;
                I = bestv;
            }
        }
        // focal loss on double-softmaxed scores
        int gi = b * PP + itile * 64 + tid;
        float4 x4 = ((const float4*)xr)[gi];
        float m = fmaxf(fmaxf(x4.x, x4.y), fmaxf(x4.z, x4.w));
        float e0 = expf(x4.x - m), e1 = expf(x4.y - m), e2 = expf(x4.z - m), e3 = expf(x4.w - m);
        float ssum = e0 + e1 + e2 + e3;
        float et = (target == 0) ? e0 : (target == 1) ? e1 : (target == 2) ? e2 : e3;
        float pt = et / ssum;
        pt = fminf(fmaxf(pt, 1e-7f), 1.0f - 1e-7f);
        float fl = -logf(pt) * (1.0f - pt) * (1.0f - pt);

        float sw = wv, sf = fl;
#pragma unroll
        for (int off = 32; off > 0; off >>= 1) {
            sw += __shfl_down(sw, off);
            sf += __shfl_down(sf, off);
        }
        if (tid == 0) {
            partials[blockIdx.x * 2 + 0] = sw;
            partials[blockIdx.x * 2 + 1] = sf;
        }
    }
}

// ---------------------------------------------------------------------------
// K4: deterministic finalize: loss = mean(w) * mean(floss)
// ---------------------------------------------------------------------------
__global__ void __launch_bounds__(256) finalize_kernel(
    const float* __restrict__ partials, float* __restrict__ out_loss)
{
    __shared__ float swL[256], sfL[256];
    int tid = threadIdx.x;
    float sw = 0.f, sf = 0.f;
    for (int t = tid; t < NBLK_MAIN; t += 256) {
        sw += partials[2 * t];
        sf += partials[2 * t + 1];
    }
    swL[tid] = sw; sfL[tid] = sf;
    __syncthreads();
    for (int s = 128; s > 0; s >>= 1) {
        if (tid < s) { swL[tid] += swL[tid + s]; sfL[tid] += sfL[tid + s]; }
        __syncthreads();
    }
    if (tid == 0)
        out_loss[0] = (swL[0] / (float)NROW) * (sfL[0] / (float)NROW);
}

// ---------------------------------------------------------------------------
extern "C" void kernel_launch(void* const* d_in, const int* in_sizes, int n_in,
                              void* d_out, int out_size, void* d_ws, size_t ws_size,
                              hipStream_t stream)
{
    const float* inputs    = (const float*)d_in[0];
    const float* pre_score = (const float*)d_in[1];
    const int*   labels    = (const int*)d_in[2];
    const float* rois      = (const float*)d_in[3];
    // d_in[4] = num (2048, fixed)
    const float* fc_w      = (const float*)d_in[5];
    const float* fc_b      = (const float*)d_in[6];

    float* out = (float*)d_out;
    float* recs     = (float*)d_ws;                                   // 1 MiB
    float* partials = (float*)((char*)d_ws + (size_t)BS * PP * 8 * 4);

    prep_kernel<<<BS, 256, 0, stream>>>(pre_score, rois, recs);
    fc_softmax_kernel<<<NROW / 4, 256, 0, stream>>>(inputs, fc_w, fc_b, out);
    main_kernel<<<NBLK_MAIN, 512, 0, stream>>>(recs, pre_score, labels, out, partials);
    finalize_kernel<<<1, 256, 0, stream>>>(partials, out + (size_t)NROW * 4);
}

// Round 4
// 99.092 us; speedup vs baseline: 1.2758x; 1.0302x over previous
//
#include <hip/hip_runtime.h>
#include <math.h>

#define BS   16
#define PP   2048
#define CIN  500
#define NROW (BS * PP)            // 32768
#define ITILES 32                 // 64-row i-tiles per batch
#define NBT   (BS * ITILES)       // 512 (b,itile) pairs
#define NBLK_MAIN (NBT * 2)       // 1024 iou blocks (2 j-halves)
#define HALF_J 1024

// ---------------------------------------------------------------------------
// K1: xr_k = softmax(inputs @ fc_w^T + fc_b); 4 rows per wave, 16 per block.
// ---------------------------------------------------------------------------
__global__ void __launch_bounds__(256) fc_softmax_kernel(
    const float* __restrict__ inputs, const float* __restrict__ fc_w,
    const float* __restrict__ fc_b, float* __restrict__ out)
{
    __shared__ float4 wL[CIN];
    int tid = threadIdx.x;
    for (int k = tid; k < CIN; k += 256)
        wL[k] = make_float4(fc_w[k], fc_w[CIN + k], fc_w[2 * CIN + k], fc_w[3 * CIN + k]);
    __syncthreads();

    int lane = tid & 63;
    int wv   = tid >> 6;
#pragma unroll
    for (int r = 0; r < 4; ++r) {
        int row = blockIdx.x * 16 + wv * 4 + r;
        const float4* in4 = (const float4*)(inputs + (size_t)row * CIN);
        float a0 = 0.f, a1 = 0.f, a2 = 0.f, a3 = 0.f;
#pragma unroll
        for (int t = 0; t < 2; ++t) {
            int f = t * 64 + lane;          // 125 float4 per row
            if (f < 125) {
                float4 x = in4[f];
                float4 w0 = wL[f * 4 + 0], w1 = wL[f * 4 + 1];
                float4 w2 = wL[f * 4 + 2], w3 = wL[f * 4 + 3];
                a0 += x.x * w0.x + x.y * w1.x + x.z * w2.x + x.w * w3.x;
                a1 += x.x * w0.y + x.y * w1.y + x.z * w2.y + x.w * w3.y;
                a2 += x.x * w0.z + x.y * w1.z + x.z * w2.z + x.w * w3.z;
                a3 += x.x * w0.w + x.y * w1.w + x.z * w2.w + x.w * w3.w;
            }
        }
#pragma unroll
        for (int off = 32; off > 0; off >>= 1) {
            a0 += __shfl_xor(a0, off);
            a1 += __shfl_xor(a1, off);
            a2 += __shfl_xor(a2, off);
            a3 += __shfl_xor(a3, off);
        }
        if (lane == 0) {
            a0 += fc_b[0]; a1 += fc_b[1]; a2 += fc_b[2]; a3 += fc_b[3];
            float m = fmaxf(fmaxf(a0, a1), fmaxf(a2, a3));
            float e0 = expf(a0 - m), e1 = expf(a1 - m), e2 = expf(a2 - m), e3 = expf(a3 - m);
            float inv = 1.0f / (e0 + e1 + e2 + e3);
            ((float4*)out)[row] = make_float4(e0 * inv, e1 * inv, e2 * inv, e3 * inv);
        }
    }
}

// ---------------------------------------------------------------------------
// K2: candidate bits per (b,j): score>0.5, fallback to first-argmax one-hot
// when count<=1. 3 bits packed per byte.
// ---------------------------------------------------------------------------
__global__ void __launch_bounds__(256) cand_kernel(
    const float* __restrict__ pre_score, unsigned char* __restrict__ packed)
{
    int b = blockIdx.x;
    int tid = threadIdx.x;
    __shared__ float sv[256];
    __shared__ int   si[256];
    __shared__ int   sc[256];

    unsigned char bits[8];
    float myv[8];
#pragma unroll
    for (int t = 0; t < 8; ++t) bits[t] = 0;

    for (int c = 0; c < 3; ++c) {
        float bv = -1.0f; int bi = 0; int cnt = 0;
#pragma unroll
        for (int t = 0; t < 8; ++t) {
            int j = t * 256 + tid;      // ascending j per thread
            float v = pre_score[((size_t)b * PP + j) * 3 + c];
            myv[t] = v;
            if (v > 0.5f) cnt++;
            if (v > bv) { bv = v; bi = j; }   // strict > => first max
        }
        sv[tid] = bv; si[tid] = bi; sc[tid] = cnt;
        __syncthreads();
        for (int s2 = 128; s2 > 0; s2 >>= 1) {
            if (tid < s2) {
                float ov = sv[tid + s2]; int oi = si[tid + s2];
                if (ov > sv[tid] || (ov == sv[tid] && oi < si[tid])) { sv[tid] = ov; si[tid] = oi; }
                sc[tid] += sc[tid + s2];
            }
            __syncthreads();
        }
        int total = sc[0];
        int amax  = si[0];
        __syncthreads();
#pragma unroll
        for (int t = 0; t < 8; ++t) {
            int j = t * 256 + tid;
            bool cb = (total <= 1) ? (j == amax) : (myv[t] > 0.5f);
            if (cb) bits[t] |= (unsigned char)(1 << c);
        }
    }
#pragma unroll
    for (int t = 0; t < 8; ++t)
        packed[(size_t)b * PP + t * 256 + tid] = bits[t];
}

// ---------------------------------------------------------------------------
// K3: iou — block = 512 thr (8 waves), covers 64 i's x 1024 j's (one half).
// Wave w scans j-local in [128w, 128w+128) ascending (first-max ties).
// Box broadcast: ds_read_b128 + ds_read_b32 (area). Candidate bias via
// per-lane cand words + readlane (uniform -> SALU). Writes per-class (best,j).
// ---------------------------------------------------------------------------
__global__ void __launch_bounds__(512) iou_kernel(
    const float* __restrict__ rois, const unsigned char* __restrict__ packed,
    float2* __restrict__ halfres)
{
    __shared__ float4 boxesL[HALF_J];   // 16 KiB
    __shared__ float  areaL[HALF_J];    // 4 KiB
    int bid  = blockIdx.x;
    int half = bid & 1;
    int bt   = bid >> 1;
    int b    = bt >> 5;
    int itile = bt & 31;
    int tid  = threadIdx.x;

    const float4* rbase = (const float4*)(rois + (size_t)b * PP * 4);
    const float4* rb = rbase + half * HALF_J;
    for (int t = tid; t < HALF_J; t += 512) {
        float4 bx = rb[t];
        boxesL[t] = bx;
        areaL[t]  = (bx.z - bx.x) * (bx.w - bx.y);
    }
    __syncthreads();

    int lane = tid & 63, w = tid >> 6;
    int i = itile * 64 + lane;
    float4 bi = rbase[i];
    float  ai = (bi.z - bi.x) * (bi.w - bi.y);

    int jb = w * 128;   // local j base for this wave
    // lane m (m = lane&31) caches cand bytes for local j = jb + 4m .. 4m+3
    unsigned int cword = ((const unsigned int*)(packed + (size_t)b * PP + half * HALF_J))
                         [(jb >> 2) + (lane & 31)];

    float best0 = -1.f, best1 = -1.f, best2 = -1.f;
    int   j0 = 0, j1 = 0, j2 = 0;
#pragma unroll 8
    for (int jj = 0; jj < 128; ++jj) {
        int j = jb + jj;
        float4 bj = boxesL[j];
        float  aj = areaL[j];
        unsigned int bb = ((unsigned int)__builtin_amdgcn_readlane((int)cword, jj >> 2)
                           >> (8 * (jj & 3))) & 0xffu;
        float b0 = (bb & 1u) ? 0.0f : -3.0f;
        float b1 = (bb & 2u) ? 0.0f : -3.0f;
        float b2 = (bb & 4u) ? 0.0f : -3.0f;
        float lx = fmaxf(bi.x, bj.x);
        float ly = fmaxf(bi.y, bj.y);
        float rx = fminf(bi.z, bj.z);
        float ry = fminf(bi.w, bj.w);
        float ww = fmaxf(rx - lx, 0.f);
        float hh = fmaxf(ry - ly, 0.f);
        float inter = ww * hh;
        float uni   = ai + aj - inter;
        float iou   = __fdividef(inter, uni);
        float k0 = iou + b0;
        float k1 = iou + b1;
        float k2 = iou + b2;
        if (k0 > best0) { best0 = k0; j0 = j; }
        if (k1 > best1) { best1 = k1; j1 = j; }
        if (k2 > best2) { best2 = k2; j2 = j; }
    }
    __syncthreads();                       // done reading staged boxes
    float* bestA = (float*)boxesL;         // [3][8][64] floats (6 KiB)
    int*   jA    = (int*)boxesL + 1536;    // [3][8][64] ints   (6 KiB)
    bestA[(0 * 8 + w) * 64 + lane] = best0; jA[(0 * 8 + w) * 64 + lane] = j0;
    bestA[(1 * 8 + w) * 64 + lane] = best1; jA[(1 * 8 + w) * 64 + lane] = j1;
    bestA[(2 * 8 + w) * 64 + lane] = best2; jA[(2 * 8 + w) * 64 + lane] = j2;
    __syncthreads();

    if (tid < 64) {
#pragma unroll
        for (int c = 0; c < 3; ++c) {
            float v = bestA[c * 512 + tid];
            int  jv = jA[c * 512 + tid];
#pragma unroll
            for (int w2 = 1; w2 < 8; ++w2) {
                float ov = bestA[c * 512 + w2 * 64 + tid];
                int   oi = jA[c * 512 + w2 * 64 + tid];
                if (ov > v) { v = ov; jv = oi; }  // strict >: lower wave (smaller j) wins ties
            }
            float2 r;
            r.x = v;
            r.y = __int_as_float(jv + half * HALF_J);  // global j
            halfres[(size_t)bid * 192 + c * 64 + tid] = r;
        }
    }
}

// ---------------------------------------------------------------------------
// K4: merge halves + sequential class logic + focal loss; per-(b,itile)
// partial sums. 512 blocks x 64 threads.
// ---------------------------------------------------------------------------
__global__ void __launch_bounds__(64) merge_focal_kernel(
    const float2* __restrict__ halfres, const float* __restrict__ pre_score,
    const int* __restrict__ labels, const float* __restrict__ xr,
    float* __restrict__ partials)
{
    int bt = blockIdx.x;
    int b = bt >> 5, itile = bt & 31;
    int tid = threadIdx.x;   // 0..63, the i within the tile

    float I = 0.f, wv = 0.f;
    int target = 3;
#pragma unroll
    for (int c = 0; c < 3; ++c) {
        float2 h0 = halfres[(size_t)(bt * 2 + 0) * 192 + c * 64 + tid];
        float2 h1 = halfres[(size_t)(bt * 2 + 1) * 192 + c * 64 + tid];
        float v = h0.x; int jv = __float_as_int(h0.y);
        if (h1.x > v) { v = h1.x; jv = __float_as_int(h1.y); }  // strict >: half0 (smaller j) wins ties
        float bestv = (labels[b * 3 + c] != 0) ? v : -1.0f;
        if (bestv > I) {
            wv = pre_score[((size_t)b * PP + jv) * 3 + c];
            if (bestv > 0.5f && target == 3) target = c;
            I = bestv;
        }
    }
    // focal loss on double-softmaxed scores
    int gi = b * PP + itile * 64 + tid;
    float4 x4 = ((const float4*)xr)[gi];
    float m = fmaxf(fmaxf(x4.x, x4.y), fmaxf(x4.z, x4.w));
    float e0 = expf(x4.x - m), e1 = expf(x4.y - m), e2 = expf(x4.z - m), e3 = expf(x4.w - m);
    float ssum = e0 + e1 + e2 + e3;
    float et = (target == 0) ? e0 : (target == 1) ? e1 : (target == 2) ? e2 : e3;
    float pt = et / ssum;
    pt = fminf(fmaxf(pt, 1e-7f), 1.0f - 1e-7f);
    float fl = -logf(pt) * (1.0f - pt) * (1.0f - pt);

    float sw = wv, sf = fl;
#pragma unroll
    for (int off = 32; off > 0; off >>= 1) {
        sw += __shfl_down(sw, off);
        sf += __shfl_down(sf, off);
    }
    if (tid == 0) {
        partials[bt * 2 + 0] = sw;
        partials[bt * 2 + 1] = sf;
    }
}

// ---------------------------------------------------------------------------
// K5: deterministic finalize: loss = mean(w) * mean(floss)
// ---------------------------------------------------------------------------
__global__ void __launch_bounds__(256) finalize_kernel(
    const float* __restrict__ partials, float* __restrict__ out_loss)
{
    __shared__ float swL[256], sfL[256];
    int tid = threadIdx.x;
    float sw = 0.f, sf = 0.f;
    for (int t = tid; t < NBT; t += 256) {
        sw += partials[2 * t];
        sf += partials[2 * t + 1];
    }
    swL[tid] = sw; sfL[tid] = sf;
    __syncthreads();
    for (int s = 128; s > 0; s >>= 1) {
        if (tid < s) { swL[tid] += swL[tid + s]; sfL[tid] += sfL[tid + s]; }
        __syncthreads();
    }
    if (tid == 0)
        out_loss[0] = (swL[0] / (float)NROW) * (sfL[0] / (float)NROW);
}

// ---------------------------------------------------------------------------
extern "C" void kernel_launch(void* const* d_in, const int* in_sizes, int n_in,
                              void* d_out, int out_size, void* d_ws, size_t ws_size,
                              hipStream_t stream)
{
    const float* inputs    = (const float*)d_in[0];
    const float* pre_score = (const float*)d_in[1];
    const int*   labels    = (const int*)d_in[2];
    const float* rois      = (const float*)d_in[3];
    // d_in[4] = num (2048, fixed)
    const float* fc_w      = (const float*)d_in[5];
    const float* fc_b      = (const float*)d_in[6];

    float* out = (float*)d_out;
    unsigned char* packed = (unsigned char*)d_ws;                      // 32 KiB
    float2* halfres = (float2*)((char*)d_ws + (size_t)BS * PP);        // 1.5 MiB
    float* partials = (float*)((char*)halfres + (size_t)NBLK_MAIN * 192 * sizeof(float2));

    cand_kernel<<<BS, 256, 0, stream>>>(pre_score, packed);
    fc_softmax_kernel<<<NROW / 16, 256, 0, stream>>>(inputs, fc_w, fc_b, out);
    iou_kernel<<<NBLK_MAIN, 512, 0, stream>>>(rois, packed, halfres);
    merge_focal_kernel<<<NBT, 64, 0, stream>>>(halfres, pre_score, labels, out, partials);
    finalize_kernel<<<1, 256, 0, stream>>>(partials, out + (size_t)NROW * 4);
}

// Round 5
// 87.920 us; speedup vs baseline: 1.4380x; 1.1271x over previous
//
#include <hip/hip_runtime.h>
#include <math.h>

#define BS   16
#define PP   2048
#define CIN  500
#define NROW (BS * PP)            // 32768
#define ITILES 32                 // 64-row i-tiles per batch
#define NBT   (BS * ITILES)       // 512 (b,itile) pairs
#define NBLK_MAIN (NBT * 2)       // 1024 iou blocks (2 j-halves)
#define HALF_J 1024

// ---------------------------------------------------------------------------
// K1: xr_k = softmax(inputs @ fc_w^T + fc_b); 4 rows per wave, 16 per block.
// ---------------------------------------------------------------------------
__global__ void __launch_bounds__(256) fc_softmax_kernel(
    const float* __restrict__ inputs, const float* __restrict__ fc_w,
    const float* __restrict__ fc_b, float* __restrict__ out)
{
    __shared__ float4 wL[CIN];
    int tid = threadIdx.x;
    for (int k = tid; k < CIN; k += 256)
        wL[k] = make_float4(fc_w[k], fc_w[CIN + k], fc_w[2 * CIN + k], fc_w[3 * CIN + k]);
    __syncthreads();

    int lane = tid & 63;
    int wv   = tid >> 6;
#pragma unroll
    for (int r = 0; r < 4; ++r) {
        int row = blockIdx.x * 16 + wv * 4 + r;
        const float4* in4 = (const float4*)(inputs + (size_t)row * CIN);
        float a0 = 0.f, a1 = 0.f, a2 = 0.f, a3 = 0.f;
#pragma unroll
        for (int t = 0; t < 2; ++t) {
            int f = t * 64 + lane;          // 125 float4 per row
            if (f < 125) {
                float4 x = in4[f];
                float4 w0 = wL[f * 4 + 0], w1 = wL[f * 4 + 1];
                float4 w2 = wL[f * 4 + 2], w3 = wL[f * 4 + 3];
                a0 += x.x * w0.x + x.y * w1.x + x.z * w2.x + x.w * w3.x;
                a1 += x.x * w0.y + x.y * w1.y + x.z * w2.y + x.w * w3.y;
                a2 += x.x * w0.z + x.y * w1.z + x.z * w2.z + x.w * w3.z;
                a3 += x.x * w0.w + x.y * w1.w + x.z * w2.w + x.w * w3.w;
            }
        }
#pragma unroll
        for (int off = 32; off > 0; off >>= 1) {
            a0 += __shfl_xor(a0, off);
            a1 += __shfl_xor(a1, off);
            a2 += __shfl_xor(a2, off);
            a3 += __shfl_xor(a3, off);
        }
        if (lane == 0) {
            a0 += fc_b[0]; a1 += fc_b[1]; a2 += fc_b[2]; a3 += fc_b[3];
            float m = fmaxf(fmaxf(a0, a1), fmaxf(a2, a3));
            float e0 = expf(a0 - m), e1 = expf(a1 - m), e2 = expf(a2 - m), e3 = expf(a3 - m);
            float inv = 1.0f / (e0 + e1 + e2 + e3);
            ((float4*)out)[row] = make_float4(e0 * inv, e1 * inv, e2 * inv, e3 * inv);
        }
    }
}

// ---------------------------------------------------------------------------
// K2: candidate bits per (b,j): score>0.5, fallback to first-argmax one-hot
// when count<=1. 3 bits packed per byte.
// ---------------------------------------------------------------------------
__global__ void __launch_bounds__(256) cand_kernel(
    const float* __restrict__ pre_score, unsigned char* __restrict__ packed)
{
    int b = blockIdx.x;
    int tid = threadIdx.x;
    __shared__ float sv[256];
    __shared__ int   si[256];
    __shared__ int   sc[256];

    unsigned char bits[8];
    float myv[8];
#pragma unroll
    for (int t = 0; t < 8; ++t) bits[t] = 0;

    for (int c = 0; c < 3; ++c) {
        float bv = -1.0f; int bi = 0; int cnt = 0;
#pragma unroll
        for (int t = 0; t < 8; ++t) {
            int j = t * 256 + tid;      // ascending j per thread
            float v = pre_score[((size_t)b * PP + j) * 3 + c];
            myv[t] = v;
            if (v > 0.5f) cnt++;
            if (v > bv) { bv = v; bi = j; }   // strict > => first max
        }
        sv[tid] = bv; si[tid] = bi; sc[tid] = cnt;
        __syncthreads();
        for (int s2 = 128; s2 > 0; s2 >>= 1) {
            if (tid < s2) {
                float ov = sv[tid + s2]; int oi = si[tid + s2];
                if (ov > sv[tid] || (ov == sv[tid] && oi < si[tid])) { sv[tid] = ov; si[tid] = oi; }
                sc[tid] += sc[tid + s2];
            }
            __syncthreads();
        }
        int total = sc[0];
        int amax  = si[0];
        __syncthreads();
#pragma unroll
        for (int t = 0; t < 8; ++t) {
            int j = t * 256 + tid;
            bool cb = (total <= 1) ? (j == amax) : (myv[t] > 0.5f);
            if (cb) bits[t] |= (unsigned char)(1 << c);
        }
    }
#pragma unroll
    for (int t = 0; t < 8; ++t)
        packed[(size_t)b * PP + t * 256 + tid] = bits[t];
}

// ---------------------------------------------------------------------------
// K3: iou — block = 512 thr (8 waves), covers 64 i's x 1024 j's (one half).
// Wave w scans j-local in [128w, 128w+128) ascending (first-max ties).
// Box broadcast: ds_read_b128 + ds_read_b32 (area). Candidate bias via
// per-lane cand words + readlane (uniform -> SALU). iou via v_rcp (fast
// approx; only feeds argmax compares + 0.5 threshold -> epsilon-safe).
// ---------------------------------------------------------------------------
__global__ void __launch_bounds__(512) iou_kernel(
    const float* __restrict__ rois, const unsigned char* __restrict__ packed,
    float2* __restrict__ halfres)
{
    __shared__ float4 boxesL[HALF_J];   // 16 KiB
    __shared__ float  areaL[HALF_J];    // 4 KiB
    int bid  = blockIdx.x;
    int half = bid & 1;
    int bt   = bid >> 1;
    int b    = bt >> 5;
    int itile = bt & 31;
    int tid  = threadIdx.x;

    const float4* rbase = (const float4*)(rois + (size_t)b * PP * 4);
    const float4* rb = rbase + half * HALF_J;
    for (int t = tid; t < HALF_J; t += 512) {
        float4 bx = rb[t];
        boxesL[t] = bx;
        areaL[t]  = (bx.z - bx.x) * (bx.w - bx.y);
    }
    __syncthreads();

    int lane = tid & 63, w = tid >> 6;
    int i = itile * 64 + lane;
    float4 bi = rbase[i];
    float  ai = (bi.z - bi.x) * (bi.w - bi.y);

    int jb = w * 128;   // local j base for this wave
    // lane m (m = lane&31) caches cand bytes for local j = jb + 4m .. 4m+3
    unsigned int cword = ((const unsigned int*)(packed + (size_t)b * PP + half * HALF_J))
                         [(jb >> 2) + (lane & 31)];

    float best0 = -1.f, best1 = -1.f, best2 = -1.f;
    int   j0 = 0, j1 = 0, j2 = 0;
#pragma unroll 8
    for (int jj = 0; jj < 128; ++jj) {
        int j = jb + jj;
        float4 bj = boxesL[j];
        float  aj = areaL[j];
        unsigned int bb = ((unsigned int)__builtin_amdgcn_readlane((int)cword, jj >> 2)
                           >> (8 * (jj & 3))) & 0xffu;
        float b0 = (bb & 1u) ? 0.0f : -3.0f;
        float b1 = (bb & 2u) ? 0.0f : -3.0f;
        float b2 = (bb & 4u) ? 0.0f : -3.0f;
        float lx = fmaxf(bi.x, bj.x);
        float ly = fmaxf(bi.y, bj.y);
        float rx = fminf(bi.z, bj.z);
        float ry = fminf(bi.w, bj.w);
        float ww = fmaxf(rx - lx, 0.f);
        float hh = fmaxf(ry - ly, 0.f);
        float inter = ww * hh;
        float uni   = ai + aj - inter;
        float iou   = inter * __builtin_amdgcn_rcpf(uni);   // fast rcp, no div sequence
        float k0 = iou + b0;
        float k1 = iou + b1;
        float k2 = iou + b2;
        if (k0 > best0) { best0 = k0; j0 = j; }
        if (k1 > best1) { best1 = k1; j1 = j; }
        if (k2 > best2) { best2 = k2; j2 = j; }
    }
    __syncthreads();                       // done reading staged boxes
    float* bestA = (float*)boxesL;         // [3][8][64] floats (6 KiB)
    int*   jA    = (int*)boxesL + 1536;    // [3][8][64] ints   (6 KiB)
    bestA[(0 * 8 + w) * 64 + lane] = best0; jA[(0 * 8 + w) * 64 + lane] = j0;
    bestA[(1 * 8 + w) * 64 + lane] = best1; jA[(1 * 8 + w) * 64 + lane] = j1;
    bestA[(2 * 8 + w) * 64 + lane] = best2; jA[(2 * 8 + w) * 64 + lane] = j2;
    __syncthreads();

    if (tid < 64) {
#pragma unroll
        for (int c = 0; c < 3; ++c) {
            float v = bestA[c * 512 + tid];
            int  jv = jA[c * 512 + tid];
#pragma unroll
            for (int w2 = 1; w2 < 8; ++w2) {
                float ov = bestA[c * 512 + w2 * 64 + tid];
                int   oi = jA[c * 512 + w2 * 64 + tid];
                if (ov > v) { v = ov; jv = oi; }  // strict >: lower wave (smaller j) wins ties
            }
            float2 r;
            r.x = v;
            r.y = __int_as_float(jv + half * HALF_J);  // global j
            halfres[(size_t)bid * 192 + c * 64 + tid] = r;
        }
    }
}

// ---------------------------------------------------------------------------
// K4: merge halves + sequential class logic + focal loss; per-(b,itile)
// partial sums. 512 blocks x 64 threads.
// ---------------------------------------------------------------------------
__global__ void __launch_bounds__(64) merge_focal_kernel(
    const float2* __restrict__ halfres, const float* __restrict__ pre_score,
    const int* __restrict__ labels, const float* __restrict__ xr,
    float* __restrict__ partials)
{
    int bt = blockIdx.x;
    int b = bt >> 5, itile = bt & 31;
    int tid = threadIdx.x;   // 0..63, the i within the tile

    float I = 0.f, wv = 0.f;
    int target = 3;
#pragma unroll
    for (int c = 0; c < 3; ++c) {
        float2 h0 = halfres[(size_t)(bt * 2 + 0) * 192 + c * 64 + tid];
        float2 h1 = halfres[(size_t)(bt * 2 + 1) * 192 + c * 64 + tid];
        float v = h0.x; int jv = __float_as_int(h0.y);
        if (h1.x > v) { v = h1.x; jv = __float_as_int(h1.y); }  // strict >: half0 (smaller j) wins ties
        float bestv = (labels[b * 3 + c] != 0) ? v : -1.0f;
        if (bestv > I) {
            wv = pre_score[((size_t)b * PP + jv) * 3 + c];
            if (bestv > 0.5f && target == 3) target = c;
            I = bestv;
        }
    }
    // focal loss on double-softmaxed scores
    int gi = b * PP + itile * 64 + tid;
    float4 x4 = ((const float4*)xr)[gi];
    float m = fmaxf(fmaxf(x4.x, x4.y), fmaxf(x4.z, x4.w));
    float e0 = expf(x4.x - m), e1 = expf(x4.y - m), e2 = expf(x4.z - m), e3 = expf(x4.w - m);
    float ssum = e0 + e1 + e2 + e3;
    float et = (target == 0) ? e0 : (target == 1) ? e1 : (target == 2) ? e2 : e3;
    float pt = et / ssum;
    pt = fminf(fmaxf(pt, 1e-7f), 1.0f - 1e-7f);
    float fl = -logf(pt) * (1.0f - pt) * (1.0f - pt);

    float sw = wv, sf = fl;
#pragma unroll
    for (int off = 32; off > 0; off >>= 1) {
        sw += __shfl_down(sw, off);
        sf += __shfl_down(sf, off);
    }
    if (tid == 0) {
        partials[bt * 2 + 0] = sw;
        partials[bt * 2 + 1] = sf;
    }
}

// ---------------------------------------------------------------------------
// K5: deterministic finalize: loss = mean(w) * mean(floss)
// ---------------------------------------------------------------------------
__global__ void __launch_bounds__(256) finalize_kernel(
    const float* __restrict__ partials, float* __restrict__ out_loss)
{
    __shared__ float swL[256], sfL[256];
    int tid = threadIdx.x;
    float sw = 0.f, sf = 0.f;
    for (int t = tid; t < NBT; t += 256) {
        sw += partials[2 * t];
        sf += partials[2 * t + 1];
    }
    swL[tid] = sw; sfL[tid] = sf;
    __syncthreads();
    for (int s = 128; s > 0; s >>= 1) {
        if (tid < s) { swL[tid] += swL[tid + s]; sfL[tid] += sfL[tid + s]; }
        __syncthreads();
    }
    if (tid == 0)
        out_loss[0] = (swL[0] / (float)NROW) * (sfL[0] / (float)NROW);
}

// ---------------------------------------------------------------------------
extern "C" void kernel_launch(void* const* d_in, const int* in_sizes, int n_in,
                              void* d_out, int out_size, void* d_ws, size_t ws_size,
                              hipStream_t stream)
{
    const float* inputs    = (const float*)d_in[0];
    const float* pre_score = (const float*)d_in[1];
    const int*   labels    = (const int*)d_in[2];
    const float* rois      = (const float*)d_in[3];
    // d_in[4] = num (2048, fixed)
    const float* fc_w      = (const float*)d_in[5];
    const float* fc_b      = (const float*)d_in[6];

    float* out = (float*)d_out;
    unsigned char* packed = (unsigned char*)d_ws;                      // 32 KiB
    float2* halfres = (float2*)((char*)d_ws + (size_t)BS * PP);        // 1.5 MiB
    float* partials = (float*)((char*)halfres + (size_t)NBLK_MAIN * 192 * sizeof(float2));

    cand_kernel<<<BS, 256, 0, stream>>>(pre_score, packed);
    fc_softmax_kernel<<<NROW / 16, 256, 0, stream>>>(inputs, fc_w, fc_b, out);
    iou_kernel<<<NBLK_MAIN, 512, 0, stream>>>(rois, packed, halfres);
    merge_focal_kernel<<<NBT, 64, 0, stream>>>(halfres, pre_score, labels, out, partials);
    finalize_kernel<<<1, 256, 0, stream>>>(partials, out + (size_t)NROW * 4);
}

// Round 6
// 85.902 us; speedup vs baseline: 1.4717x; 1.0235x over previous
//
#include <hip/hip_runtime.h>
#include <math.h>

#define BS   16
#define PP   2048
#define CIN  500
#define NROW (BS * PP)            // 32768
#define JQ   512                  // j's per iou block (quarter)
#define NQ   4                    // j quarters
#define IT   128                  // i's per iou block
#define NIT  16                   // i tiles per batch
#define NBLK_IOU (BS * NIT * NQ)  // 1024
#define NBT2 (BS * NIT)           // 256 merge blocks

// ---------------------------------------------------------------------------
// K1: xr_k = softmax(inputs @ fc_w^T + fc_b); 4 rows per wave, 16 per block.
// ---------------------------------------------------------------------------
__global__ void __launch_bounds__(256) fc_softmax_kernel(
    const float* __restrict__ inputs, const float* __restrict__ fc_w,
    const float* __restrict__ fc_b, float* __restrict__ out)
{
    __shared__ float4 wL[CIN];
    int tid = threadIdx.x;
    for (int k = tid; k < CIN; k += 256)
        wL[k] = make_float4(fc_w[k], fc_w[CIN + k], fc_w[2 * CIN + k], fc_w[3 * CIN + k]);
    __syncthreads();

    int lane = tid & 63;
    int wv   = tid >> 6;
#pragma unroll
    for (int r = 0; r < 4; ++r) {
        int row = blockIdx.x * 16 + wv * 4 + r;
        const float4* in4 = (const float4*)(inputs + (size_t)row * CIN);
        float a0 = 0.f, a1 = 0.f, a2 = 0.f, a3 = 0.f;
#pragma unroll
        for (int t = 0; t < 2; ++t) {
            int f = t * 64 + lane;          // 125 float4 per row
            if (f < 125) {
                float4 x = in4[f];
                float4 w0 = wL[f * 4 + 0], w1 = wL[f * 4 + 1];
                float4 w2 = wL[f * 4 + 2], w3 = wL[f * 4 + 3];
                a0 += x.x * w0.x + x.y * w1.x + x.z * w2.x + x.w * w3.x;
                a1 += x.x * w0.y + x.y * w1.y + x.z * w2.y + x.w * w3.y;
                a2 += x.x * w0.z + x.y * w1.z + x.z * w2.z + x.w * w3.z;
                a3 += x.x * w0.w + x.y * w1.w + x.z * w2.w + x.w * w3.w;
            }
        }
#pragma unroll
        for (int off = 32; off > 0; off >>= 1) {
            a0 += __shfl_xor(a0, off);
            a1 += __shfl_xor(a1, off);
            a2 += __shfl_xor(a2, off);
            a3 += __shfl_xor(a3, off);
        }
        if (lane == 0) {
            a0 += fc_b[0]; a1 += fc_b[1]; a2 += fc_b[2]; a3 += fc_b[3];
            float m = fmaxf(fmaxf(a0, a1), fmaxf(a2, a3));
            float e0 = expf(a0 - m), e1 = expf(a1 - m), e2 = expf(a2 - m), e3 = expf(a3 - m);
            float inv = 1.0f / (e0 + e1 + e2 + e3);
            ((float4*)out)[row] = make_float4(e0 * inv, e1 * inv, e2 * inv, e3 * inv);
        }
    }
}

// ---------------------------------------------------------------------------
// K2: candidate bits per (b,j): score>0.5, fallback to first-argmax one-hot
// when count<=1. 3 bits packed per byte.
// ---------------------------------------------------------------------------
__global__ void __launch_bounds__(256) cand_kernel(
    const float* __restrict__ pre_score, unsigned char* __restrict__ packed)
{
    int b = blockIdx.x;
    int tid = threadIdx.x;
    __shared__ float sv[256];
    __shared__ int   si[256];
    __shared__ int   sc[256];

    unsigned char bits[8];
    float myv[8];
#pragma unroll
    for (int t = 0; t < 8; ++t) bits[t] = 0;

    for (int c = 0; c < 3; ++c) {
        float bv = -1.0f; int bi = 0; int cnt = 0;
#pragma unroll
        for (int t = 0; t < 8; ++t) {
            int j = t * 256 + tid;      // ascending j per thread
            float v = pre_score[((size_t)b * PP + j) * 3 + c];
            myv[t] = v;
            if (v > 0.5f) cnt++;
            if (v > bv) { bv = v; bi = j; }   // strict > => first max
        }
        sv[tid] = bv; si[tid] = bi; sc[tid] = cnt;
        __syncthreads();
        for (int s2 = 128; s2 > 0; s2 >>= 1) {
            if (tid < s2) {
                float ov = sv[tid + s2]; int oi = si[tid + s2];
                if (ov > sv[tid] || (ov == sv[tid] && oi < si[tid])) { sv[tid] = ov; si[tid] = oi; }
                sc[tid] += sc[tid + s2];
            }
            __syncthreads();
        }
        int total = sc[0];
        int amax  = si[0];
        __syncthreads();
#pragma unroll
        for (int t = 0; t < 8; ++t) {
            int j = t * 256 + tid;
            bool cb = (total <= 1) ? (j == amax) : (myv[t] > 0.5f);
            if (cb) bits[t] |= (unsigned char)(1 << c);
        }
    }
#pragma unroll
    for (int t = 0; t < 8; ++t)
        packed[(size_t)b * PP + t * 256 + tid] = bits[t];
}

// ---------------------------------------------------------------------------
// K3: iou — block = 512 thr (8 waves) covers 128 i's (2 slots/lane) x 512 j's
// (one quarter). Wave w scans local j in [64w, 64w+64) ascending. Box+area
// broadcast from LDS; candidate bias via per-lane cand words + readlane
// (uniform -> SALU, one readlane per 4 j's). Exact first-max tie-break:
// ascending j in wave, waves merged in order, quarters merged in order (K4).
// ---------------------------------------------------------------------------
__global__ void __launch_bounds__(512) iou_kernel(
    const float* __restrict__ rois, const unsigned char* __restrict__ packed,
    float2* __restrict__ qres)
{
    __shared__ float4 boxesL[JQ];      // 8 KiB
    __shared__ float  areaL[JQ];       // 2 KiB
    __shared__ float  bestA[3][8][IT]; // 12 KiB
    __shared__ int    jA[3][8][IT];    // 12 KiB
    int bid = blockIdx.x;
    int q   = bid & 3;
    int it  = (bid >> 2) & 15;
    int b   = bid >> 6;
    int tid = threadIdx.x;

    const float4* rbase = (const float4*)(rois + (size_t)b * PP * 4);
    const float4* rq = rbase + q * JQ;
    for (int t = tid; t < JQ; t += 512) {
        float4 bx = rq[t];
        boxesL[t] = bx;
        areaL[t]  = (bx.z - bx.x) * (bx.w - bx.y);
    }
    __syncthreads();

    int lane = tid & 63, w = tid >> 6;
    int i0 = it * IT + lane;           // slot 0
    int i1 = i0 + 64;                  // slot 1
    float4 bi0 = rbase[i0];
    float4 bi1 = rbase[i1];
    float  ai0 = (bi0.z - bi0.x) * (bi0.w - bi0.y);
    float  ai1 = (bi1.z - bi1.x) * (bi1.w - bi1.y);

    int jb = w * 64;  // local j base for this wave
    // lane m (m = lane&15) holds cand word for local j in [jb+4m, jb+4m+4)
    unsigned int cword = ((const unsigned int*)(packed + (size_t)b * PP + q * JQ))
                         [(jb >> 2) + (lane & 15)];

    float best0a = -1.f, best1a = -1.f, best2a = -1.f;
    float best0b = -1.f, best1b = -1.f, best2b = -1.f;
    int   j0a = 0, j1a = 0, j2a = 0, j0b = 0, j1b = 0, j2b = 0;
#pragma unroll 4
    for (int jj = 0; jj < 64; ++jj) {
        int j = jb + jj;
        float4 bj = boxesL[j];
        float  aj = areaL[j];
        unsigned int bb = ((unsigned int)__builtin_amdgcn_readlane((int)cword, jj >> 2)
                           >> (8 * (jj & 3))) & 0xffu;
        float b0 = (bb & 1u) ? 0.0f : -3.0f;
        float b1 = (bb & 2u) ? 0.0f : -3.0f;
        float b2 = (bb & 4u) ? 0.0f : -3.0f;
        // slot 0
        {
            float lx = fmaxf(bi0.x, bj.x), ly = fmaxf(bi0.y, bj.y);
            float rx = fminf(bi0.z, bj.z), ry = fminf(bi0.w, bj.w);
            float ww = fmaxf(rx - lx, 0.f), hh = fmaxf(ry - ly, 0.f);
            float inter = ww * hh;
            float uni   = ai0 + aj - inter;
            float iou   = inter * __builtin_amdgcn_rcpf(uni);
            float k0 = iou + b0, k1 = iou + b1, k2 = iou + b2;
            if (k0 > best0a) { best0a = k0; j0a = j; }
            if (k1 > best1a) { best1a = k1; j1a = j; }
            if (k2 > best2a) { best2a = k2; j2a = j; }
        }
        // slot 1
        {
            float lx = fmaxf(bi1.x, bj.x), ly = fmaxf(bi1.y, bj.y);
            float rx = fminf(bi1.z, bj.z), ry = fminf(bi1.w, bj.w);
            float ww = fmaxf(rx - lx, 0.f), hh = fmaxf(ry - ly, 0.f);
            float inter = ww * hh;
            float uni   = ai1 + aj - inter;
            float iou   = inter * __builtin_amdgcn_rcpf(uni);
            float k0 = iou + b0, k1 = iou + b1, k2 = iou + b2;
            if (k0 > best0b) { best0b = k0; j0b = j; }
            if (k1 > best1b) { best1b = k1; j1b = j; }
            if (k2 > best2b) { best2b = k2; j2b = j; }
        }
    }
    bestA[0][w][lane]      = best0a; jA[0][w][lane]      = j0a;
    bestA[1][w][lane]      = best1a; jA[1][w][lane]      = j1a;
    bestA[2][w][lane]      = best2a; jA[2][w][lane]      = j2a;
    bestA[0][w][lane + 64] = best0b; jA[0][w][lane + 64] = j0b;
    bestA[1][w][lane + 64] = best1b; jA[1][w][lane + 64] = j1b;
    bestA[2][w][lane + 64] = best2b; jA[2][w][lane + 64] = j2b;
    __syncthreads();

    if (tid < IT) {
#pragma unroll
        for (int c = 0; c < 3; ++c) {
            float v = bestA[c][0][tid];
            int  jv = jA[c][0][tid];
#pragma unroll
            for (int w2 = 1; w2 < 8; ++w2) {
                float ov = bestA[c][w2][tid];
                int   oi = jA[c][w2][tid];
                if (ov > v) { v = ov; jv = oi; }  // strict >: lower wave (smaller j) wins ties
            }
            float2 r;
            r.x = v;
            r.y = __int_as_float(jv + q * JQ);    // global j in batch
            qres[(((size_t)b * NQ + q) * 3 + c) * PP + it * IT + tid] = r;
        }
    }
}

// ---------------------------------------------------------------------------
// K4: merge quarters + sequential class logic + focal loss; per-(b,it)
// partial sums. 256 blocks x 128 threads.
// ---------------------------------------------------------------------------
__global__ void __launch_bounds__(128) merge_focal_kernel(
    const float2* __restrict__ qres, const float* __restrict__ pre_score,
    const int* __restrict__ labels, const float* __restrict__ xr,
    float* __restrict__ partials)
{
    __shared__ float redw[2], redf[2];
    int bt = blockIdx.x;
    int b = bt >> 4, it = bt & 15;
    int tid = threadIdx.x;   // 0..127
    int i = it * IT + tid;

    float I = 0.f, wv = 0.f;
    int target = 3;
#pragma unroll
    for (int c = 0; c < 3; ++c) {
        float v = -2.f; int jv = 0;
#pragma unroll
        for (int qq = 0; qq < NQ; ++qq) {
            float2 h = qres[(((size_t)b * NQ + qq) * 3 + c) * PP + i];
            if (h.x > v) { v = h.x; jv = __float_as_int(h.y); }  // ascending q => first-max
        }
        float bestv = (labels[b * 3 + c] != 0) ? v : -1.0f;
        if (bestv > I) {
            wv = pre_score[((size_t)b * PP + jv) * 3 + c];
            if (bestv > 0.5f && target == 3) target = c;
            I = bestv;
        }
    }
    // focal loss on double-softmaxed scores
    int gi = b * PP + i;
    float4 x4 = ((const float4*)xr)[gi];
    float m = fmaxf(fmaxf(x4.x, x4.y), fmaxf(x4.z, x4.w));
    float e0 = expf(x4.x - m), e1 = expf(x4.y - m), e2 = expf(x4.z - m), e3 = expf(x4.w - m);
    float ssum = e0 + e1 + e2 + e3;
    float et = (target == 0) ? e0 : (target == 1) ? e1 : (target == 2) ? e2 : e3;
    float pt = et / ssum;
    pt = fminf(fmaxf(pt, 1e-7f), 1.0f - 1e-7f);
    float fl = -logf(pt) * (1.0f - pt) * (1.0f - pt);

    float sw = wv, sf = fl;
#pragma unroll
    for (int off = 32; off > 0; off >>= 1) {
        sw += __shfl_down(sw, off);
        sf += __shfl_down(sf, off);
    }
    if ((tid & 63) == 0) { redw[tid >> 6] = sw; redf[tid >> 6] = sf; }
    __syncthreads();
    if (tid == 0) {
        partials[bt * 2 + 0] = redw[0] + redw[1];
        partials[bt * 2 + 1] = redf[0] + redf[1];
    }
}

// ---------------------------------------------------------------------------
// K5: deterministic finalize: loss = mean(w) * mean(floss)
// ---------------------------------------------------------------------------
__global__ void __launch_bounds__(256) finalize_kernel(
    const float* __restrict__ partials, float* __restrict__ out_loss)
{
    __shared__ float swL[256], sfL[256];
    int tid = threadIdx.x;
    float sw = partials[2 * tid];
    float sf = partials[2 * tid + 1];
    swL[tid] = sw; sfL[tid] = sf;
    __syncthreads();
    for (int s = 128; s > 0; s >>= 1) {
        if (tid < s) { swL[tid] += swL[tid + s]; sfL[tid] += sfL[tid + s]; }
        __syncthreads();
    }
    if (tid == 0)
        out_loss[0] = (swL[0] / (float)NROW) * (sfL[0] / (float)NROW);
}

// ---------------------------------------------------------------------------
extern "C" void kernel_launch(void* const* d_in, const int* in_sizes, int n_in,
                              void* d_out, int out_size, void* d_ws, size_t ws_size,
                              hipStream_t stream)
{
    const float* inputs    = (const float*)d_in[0];
    const float* pre_score = (const float*)d_in[1];
    const int*   labels    = (const int*)d_in[2];
    const float* rois      = (const float*)d_in[3];
    // d_in[4] = num (2048, fixed)
    const float* fc_w      = (const float*)d_in[5];
    const float* fc_b      = (const float*)d_in[6];

    float* out = (float*)d_out;
    float2* qres = (float2*)d_ws;                                   // 3.0 MiB
    unsigned char* packed = (unsigned char*)d_ws
                          + (size_t)BS * NQ * 3 * PP * sizeof(float2);  // 32 KiB
    float* partials = (float*)(packed + (size_t)BS * PP);           // 2 KiB

    cand_kernel<<<BS, 256, 0, stream>>>(pre_score, packed);
    fc_softmax_kernel<<<NROW / 16, 256, 0, stream>>>(inputs, fc_w, fc_b, out);
    iou_kernel<<<NBLK_IOU, 512, 0, stream>>>(rois, packed, qres);
    merge_focal_kernel<<<NBT2, 128, 0, stream>>>(qres, pre_score, labels, out, partials);
    finalize_kernel<<<1, 256, 0, stream>>>(partials, out + (size_t)NROW * 4);
}

// Round 7
// 71.587 us; speedup vs baseline: 1.7660x; 1.2000x over previous
//
#include <hip/hip_runtime.h>
#include <math.h>

#define BS   16
#define PP   2048
#define CIN  500
#define NROW (BS * PP)            // 32768
#define JQ   512                  // j's per iou block (quarter)
#define NQ   4                    // j quarters
#define IT   128                  // i's per iou block
#define NIT  16                   // i tiles per batch
#define NBLK_IOU (BS * NIT * NQ)  // 1024
#define NBT2 (BS * NIT)           // 256 merge blocks
#define HIMASK 0xFFFFF800u

// ---------------------------------------------------------------------------
// K1: xr_k = softmax(inputs @ fc_w^T + fc_b); 4 rows per wave, 16 per block.
// ---------------------------------------------------------------------------
__global__ void __launch_bounds__(256) fc_softmax_kernel(
    const float* __restrict__ inputs, const float* __restrict__ fc_w,
    const float* __restrict__ fc_b, float* __restrict__ out)
{
    __shared__ float4 wL[CIN];
    int tid = threadIdx.x;
    for (int k = tid; k < CIN; k += 256)
        wL[k] = make_float4(fc_w[k], fc_w[CIN + k], fc_w[2 * CIN + k], fc_w[3 * CIN + k]);
    __syncthreads();

    int lane = tid & 63;
    int wv   = tid >> 6;
#pragma unroll
    for (int r = 0; r < 4; ++r) {
        int row = blockIdx.x * 16 + wv * 4 + r;
        const float4* in4 = (const float4*)(inputs + (size_t)row * CIN);
        float a0 = 0.f, a1 = 0.f, a2 = 0.f, a3 = 0.f;
#pragma unroll
        for (int t = 0; t < 2; ++t) {
            int f = t * 64 + lane;          // 125 float4 per row
            if (f < 125) {
                float4 x = in4[f];
                float4 w0 = wL[f * 4 + 0], w1 = wL[f * 4 + 1];
                float4 w2 = wL[f * 4 + 2], w3 = wL[f * 4 + 3];
                a0 += x.x * w0.x + x.y * w1.x + x.z * w2.x + x.w * w3.x;
                a1 += x.x * w0.y + x.y * w1.y + x.z * w2.y + x.w * w3.y;
                a2 += x.x * w0.z + x.y * w1.z + x.z * w2.z + x.w * w3.z;
                a3 += x.x * w0.w + x.y * w1.w + x.z * w2.w + x.w * w3.w;
            }
        }
#pragma unroll
        for (int off = 32; off > 0; off >>= 1) {
            a0 += __shfl_xor(a0, off);
            a1 += __shfl_xor(a1, off);
            a2 += __shfl_xor(a2, off);
            a3 += __shfl_xor(a3, off);
        }
        if (lane == 0) {
            a0 += fc_b[0]; a1 += fc_b[1]; a2 += fc_b[2]; a3 += fc_b[3];
            float m = fmaxf(fmaxf(a0, a1), fmaxf(a2, a3));
            float e0 = expf(a0 - m), e1 = expf(a1 - m), e2 = expf(a2 - m), e3 = expf(a3 - m);
            float inv = 1.0f / (e0 + e1 + e2 + e3);
            ((float4*)out)[row] = make_float4(e0 * inv, e1 * inv, e2 * inv, e3 * inv);
        }
    }
}

// ---------------------------------------------------------------------------
// K2: prep — candidate logic (score>0.5, fallback to first-argmax one-hot
// when count<=1), coalesced loads (3 contiguous dwords per j). Writes per-j
// record uint4: (area_bits, m0, m1, m2), m_c = cand ? 0xFFFFFFFF : 0.
// ---------------------------------------------------------------------------
__global__ void __launch_bounds__(256) prep_kernel(
    const float* __restrict__ pre_score, const float* __restrict__ rois,
    uint4* __restrict__ mrec)
{
    int b = blockIdx.x;
    int tid = threadIdx.x;
    __shared__ float sv[256];
    __shared__ int   si[256];
    __shared__ int   sc[256];

    float v0[8], v1[8], v2[8];
    unsigned char bits[8];
#pragma unroll
    for (int t = 0; t < 8; ++t) {
        int j = t * 256 + tid;
        const float* p = pre_score + ((size_t)b * PP + j) * 3;
        v0[t] = p[0]; v1[t] = p[1]; v2[t] = p[2];
        bits[t] = 0;
    }

#define PREP_CLASS(VV, CBIT)                                                   \
    {                                                                          \
        float bv = -1.0f; int bi = 0; int cnt = 0;                             \
        _Pragma("unroll")                                                      \
        for (int t = 0; t < 8; ++t) {                                          \
            int j = t * 256 + tid;                                             \
            float v = VV[t];                                                   \
            if (v > 0.5f) cnt++;                                               \
            if (v > bv) { bv = v; bi = j; }                                    \
        }                                                                      \
        sv[tid] = bv; si[tid] = bi; sc[tid] = cnt;                             \
        __syncthreads();                                                       \
        for (int s2 = 128; s2 > 0; s2 >>= 1) {                                 \
            if (tid < s2) {                                                    \
                float ov = sv[tid + s2]; int oi = si[tid + s2];                \
                if (ov > sv[tid] || (ov == sv[tid] && oi < si[tid])) {         \
                    sv[tid] = ov; si[tid] = oi;                                \
                }                                                              \
                sc[tid] += sc[tid + s2];                                       \
            }                                                                  \
            __syncthreads();                                                   \
        }                                                                      \
        int total = sc[0];                                                     \
        int amax  = si[0];                                                     \
        __syncthreads();                                                       \
        _Pragma("unroll")                                                      \
        for (int t = 0; t < 8; ++t) {                                          \
            int j = t * 256 + tid;                                             \
            bool cb = (total <= 1) ? (j == amax) : (VV[t] > 0.5f);             \
            if (cb) bits[t] |= (unsigned char)(CBIT);                          \
        }                                                                      \
    }

    PREP_CLASS(v0, 1)
    PREP_CLASS(v1, 2)
    PREP_CLASS(v2, 4)
#undef PREP_CLASS

    const float4* rb = (const float4*)(rois + (size_t)b * PP * 4);
#pragma unroll
    for (int t = 0; t < 8; ++t) {
        int j = t * 256 + tid;
        float4 bx = rb[j];
        float area = (bx.z - bx.x) * (bx.w - bx.y);
        uint4 r;
        r.x = __float_as_uint(area);
        r.y = (bits[t] & 1) ? 0xFFFFFFFFu : 0u;
        r.z = (bits[t] & 2) ? 0xFFFFFFFFu : 0u;
        r.w = (bits[t] & 4) ? 0xFFFFFFFFu : 0u;
        mrec[(size_t)b * PP + j] = r;
    }
}

// ---------------------------------------------------------------------------
// K3: iou — block = 512 thr (8 waves) covers 128 i's (2 slots/lane) x 512 j's
// (one quarter). Packed-key argmax: key = (iou_bits & 0xFFFFF800) | (2047-j),
// masked per class by AND with precomputed all-ones/zero mask; running max is
// v_max_u32. Tie-break exact: equal iou bits -> larger (2047-j) = smaller j.
// Masked-out j -> key 0 -> extracted best 0.0 -> never beats I (strict >).
// ---------------------------------------------------------------------------
__global__ void __launch_bounds__(512) iou_kernel(
    const float* __restrict__ rois, const uint4* __restrict__ mrec,
    unsigned* __restrict__ qres)
{
    __shared__ float4   boxesL[JQ];       // 8 KiB
    __shared__ uint4    mrecL[JQ];        // 8 KiB
    __shared__ unsigned bestA[3][8][IT];  // 12 KiB
    int bid = blockIdx.x;
    int q   = bid & 3;
    int it  = (bid >> 2) & 15;
    int b   = bid >> 6;
    int tid = threadIdx.x;

    const float4* rbase = (const float4*)(rois + (size_t)b * PP * 4);
    {
        int t = tid;   // JQ == 512 == blockDim
        boxesL[t] = rbase[q * JQ + t];
        mrecL[t]  = mrec[(size_t)b * PP + q * JQ + t];
    }
    __syncthreads();

    int lane = tid & 63, w = tid >> 6;
    int i0 = it * IT + lane;           // slot 0
    int i1 = i0 + 64;                  // slot 1
    float4 bi0 = rbase[i0];
    float4 bi1 = rbase[i1];
    float  ai0 = (bi0.z - bi0.x) * (bi0.w - bi0.y);
    float  ai1 = (bi1.z - bi1.x) * (bi1.w - bi1.y);

    int jb = w * 64;                   // local j base for this wave
    int jfbase = 2047 - q * JQ - jb;   // scalar

    unsigned best0a = 0u, best1a = 0u, best2a = 0u;
    unsigned best0b = 0u, best1b = 0u, best2b = 0u;
#pragma unroll 4
    for (int jj = 0; jj < 64; ++jj) {
        float4 bj = boxesL[jb + jj];
        uint4  mj = mrecL[jb + jj];
        float  aj = __uint_as_float(mj.x);
        unsigned jf = (unsigned)(jfbase - jj);
        // slot 0
        {
            float lx = fmaxf(bi0.x, bj.x), ly = fmaxf(bi0.y, bj.y);
            float rx = fminf(bi0.z, bj.z), ry = fminf(bi0.w, bj.w);
            float ww = fmaxf(rx - lx, 0.f), hh = fmaxf(ry - ly, 0.f);
            float inter = ww * hh;
            float uni   = ai0 + aj - inter;
            float iou   = inter * __builtin_amdgcn_rcpf(uni);
            unsigned pk = (__float_as_uint(iou) & HIMASK) | jf;
            unsigned k0 = pk & mj.y, k1 = pk & mj.z, k2 = pk & mj.w;
            best0a = best0a > k0 ? best0a : k0;
            best1a = best1a > k1 ? best1a : k1;
            best2a = best2a > k2 ? best2a : k2;
        }
        // slot 1
        {
            float lx = fmaxf(bi1.x, bj.x), ly = fmaxf(bi1.y, bj.y);
            float rx = fminf(bi1.z, bj.z), ry = fminf(bi1.w, bj.w);
            float ww = fmaxf(rx - lx, 0.f), hh = fmaxf(ry - ly, 0.f);
            float inter = ww * hh;
            float uni   = ai1 + aj - inter;
            float iou   = inter * __builtin_amdgcn_rcpf(uni);
            unsigned pk = (__float_as_uint(iou) & HIMASK) | jf;
            unsigned k0 = pk & mj.y, k1 = pk & mj.z, k2 = pk & mj.w;
            best0b = best0b > k0 ? best0b : k0;
            best1b = best1b > k1 ? best1b : k1;
            best2b = best2b > k2 ? best2b : k2;
        }
    }
    bestA[0][w][lane]      = best0a;
    bestA[1][w][lane]      = best1a;
    bestA[2][w][lane]      = best2a;
    bestA[0][w][lane + 64] = best0b;
    bestA[1][w][lane + 64] = best1b;
    bestA[2][w][lane + 64] = best2b;
    __syncthreads();

    if (tid < IT) {
#pragma unroll
        for (int c = 0; c < 3; ++c) {
            unsigned m = bestA[c][0][tid];
#pragma unroll
            for (int w2 = 1; w2 < 8; ++w2) {
                unsigned o = bestA[c][w2][tid];
                m = m > o ? m : o;
            }
            qres[(((size_t)b * NQ + q) * 3 + c) * PP + it * IT + tid] = m;
        }
    }
}

// ---------------------------------------------------------------------------
// K4: merge quarters + sequential class logic + focal loss; per-(b,it)
// partial sums. 256 blocks x 128 threads.
// ---------------------------------------------------------------------------
__global__ void __launch_bounds__(128) merge_focal_kernel(
    const unsigned* __restrict__ qres, const float* __restrict__ pre_score,
    const int* __restrict__ labels, const float* __restrict__ xr,
    float* __restrict__ partials)
{
    __shared__ float redw[2], redf[2];
    int bt = blockIdx.x;
    int b = bt >> 4, it = bt & 15;
    int tid = threadIdx.x;   // 0..127
    int i = it * IT + tid;

    float I = 0.f, wv = 0.f;
    int target = 3;
#pragma unroll
    for (int c = 0; c < 3; ++c) {
        unsigned k = 0u;
#pragma unroll
        for (int qq = 0; qq < NQ; ++qq) {
            unsigned h = qres[(((size_t)b * NQ + qq) * 3 + c) * PP + i];
            k = k > h ? k : h;   // packed keys globally unique per j
        }
        int   jv    = 2047 - (int)(k & 2047u);
        float bestv = __uint_as_float(k & HIMASK);
        bestv = (labels[b * 3 + c] != 0) ? bestv : -1.0f;
        if (bestv > I) {
            wv = pre_score[((size_t)b * PP + jv) * 3 + c];
            if (bestv > 0.5f && target == 3) target = c;
            I = bestv;
        }
    }
    // focal loss on double-softmaxed scores
    int gi = b * PP + i;
    float4 x4 = ((const float4*)xr)[gi];
    float m = fmaxf(fmaxf(x4.x, x4.y), fmaxf(x4.z, x4.w));
    float e0 = expf(x4.x - m), e1 = expf(x4.y - m), e2 = expf(x4.z - m), e3 = expf(x4.w - m);
    float ssum = e0 + e1 + e2 + e3;
    float et = (target == 0) ? e0 : (target == 1) ? e1 : (target == 2) ? e2 : e3;
    float pt = et / ssum;
    pt = fminf(fmaxf(pt, 1e-7f), 1.0f - 1e-7f);
    float fl = -logf(pt) * (1.0f - pt) * (1.0f - pt);

    float sw = wv, sf = fl;
#pragma unroll
    for (int off = 32; off > 0; off >>= 1) {
        sw += __shfl_down(sw, off);
        sf += __shfl_down(sf, off);
    }
    if ((tid & 63) == 0) { redw[tid >> 6] = sw; redf[tid >> 6] = sf; }
    __syncthreads();
    if (tid == 0) {
        partials[bt * 2 + 0] = redw[0] + redw[1];
        partials[bt * 2 + 1] = redf[0] + redf[1];
    }
}

// ---------------------------------------------------------------------------
// K5: deterministic finalize: loss = mean(w) * mean(floss)
// ---------------------------------------------------------------------------
__global__ void __launch_bounds__(256) finalize_kernel(
    const float* __restrict__ partials, float* __restrict__ out_loss)
{
    __shared__ float swL[256], sfL[256];
    int tid = threadIdx.x;
    float sw = partials[2 * tid];
    float sf = partials[2 * tid + 1];
    swL[tid] = sw; sfL[tid] = sf;
    __syncthreads();
    for (int s = 128; s > 0; s >>= 1) {
        if (tid < s) { swL[tid] += swL[tid + s]; sfL[tid] += sfL[tid + s]; }
        __syncthreads();
    }
    if (tid == 0)
        out_loss[0] = (swL[0] / (float)NROW) * (sfL[0] / (float)NROW);
}

// ---------------------------------------------------------------------------
extern "C" void kernel_launch(void* const* d_in, const int* in_sizes, int n_in,
                              void* d_out, int out_size, void* d_ws, size_t ws_size,
                              hipStream_t stream)
{
    const float* inputs    = (const float*)d_in[0];
    const float* pre_score = (const float*)d_in[1];
    const int*   labels    = (const int*)d_in[2];
    const float* rois      = (const float*)d_in[3];
    // d_in[4] = num (2048, fixed)
    const float* fc_w      = (const float*)d_in[5];
    const float* fc_b      = (const float*)d_in[6];

    float* out = (float*)d_out;
    unsigned* qres = (unsigned*)d_ws;                                  // 1.5 MiB
    uint4* mrec = (uint4*)((char*)d_ws
                 + (size_t)BS * NQ * 3 * PP * sizeof(unsigned));       // 512 KiB
    float* partials = (float*)((char*)mrec + (size_t)BS * PP * sizeof(uint4));

    prep_kernel<<<BS, 256, 0, stream>>>(pre_score, rois, mrec);
    fc_softmax_kernel<<<NROW / 16, 256, 0, stream>>>(inputs, fc_w, fc_b, out);
    iou_kernel<<<NBLK_IOU, 512, 0, stream>>>(rois, mrec, qres);
    merge_focal_kernel<<<NBT2, 128, 0, stream>>>(qres, pre_score, labels, out, partials);
    finalize_kernel<<<1, 256, 0, stream>>>(partials, out + (size_t)NROW * 4);
}

// Round 8
// 70.396 us; speedup vs baseline: 1.7959x; 1.0169x over previous
//
#include <hip/hip_runtime.h>
#include <math.h>

#define BS   16
#define PP   2048
#define CIN  500
#define NROW (BS * PP)            // 32768
#define JQ   256                  // j's per iou block
#define NQ   8                    // j slices
#define IT   256                  // i's per iou block (4 slots/lane)
#define NIT  8                    // i tiles per batch
#define NBLK_IOU (BS * NIT * NQ)  // 1024
#define NBT2 (BS * NIT)           // 128 merge blocks
#define HIMASK 0xFFFFF800u

// ---------------------------------------------------------------------------
// K1: xr_k = softmax(inputs @ fc_w^T + fc_b); 4 rows per wave, 16 per block.
// ---------------------------------------------------------------------------
__global__ void __launch_bounds__(256) fc_softmax_kernel(
    const float* __restrict__ inputs, const float* __restrict__ fc_w,
    const float* __restrict__ fc_b, float* __restrict__ out)
{
    __shared__ float4 wL[CIN];
    int tid = threadIdx.x;
    for (int k = tid; k < CIN; k += 256)
        wL[k] = make_float4(fc_w[k], fc_w[CIN + k], fc_w[2 * CIN + k], fc_w[3 * CIN + k]);
    __syncthreads();

    int lane = tid & 63;
    int wv   = tid >> 6;
#pragma unroll
    for (int r = 0; r < 4; ++r) {
        int row = blockIdx.x * 16 + wv * 4 + r;
        const float4* in4 = (const float4*)(inputs + (size_t)row * CIN);
        float a0 = 0.f, a1 = 0.f, a2 = 0.f, a3 = 0.f;
#pragma unroll
        for (int t = 0; t < 2; ++t) {
            int f = t * 64 + lane;          // 125 float4 per row
            if (f < 125) {
                float4 x = in4[f];
                float4 w0 = wL[f * 4 + 0], w1 = wL[f * 4 + 1];
                float4 w2 = wL[f * 4 + 2], w3 = wL[f * 4 + 3];
                a0 += x.x * w0.x + x.y * w1.x + x.z * w2.x + x.w * w3.x;
                a1 += x.x * w0.y + x.y * w1.y + x.z * w2.y + x.w * w3.y;
                a2 += x.x * w0.z + x.y * w1.z + x.z * w2.z + x.w * w3.z;
                a3 += x.x * w0.w + x.y * w1.w + x.z * w2.w + x.w * w3.w;
            }
        }
#pragma unroll
        for (int off = 32; off > 0; off >>= 1) {
            a0 += __shfl_xor(a0, off);
            a1 += __shfl_xor(a1, off);
            a2 += __shfl_xor(a2, off);
            a3 += __shfl_xor(a3, off);
        }
        if (lane == 0) {
            a0 += fc_b[0]; a1 += fc_b[1]; a2 += fc_b[2]; a3 += fc_b[3];
            float m = fmaxf(fmaxf(a0, a1), fmaxf(a2, a3));
            float e0 = expf(a0 - m), e1 = expf(a1 - m), e2 = expf(a2 - m), e3 = expf(a3 - m);
            float inv = 1.0f / (e0 + e1 + e2 + e3);
            ((float4*)out)[row] = make_float4(e0 * inv, e1 * inv, e2 * inv, e3 * inv);
        }
    }
}

// ---------------------------------------------------------------------------
// K2: prep — candidate logic (score>0.5, fallback to first-argmax one-hot
// when count<=1), coalesced loads. Writes per-j record uint4:
// (area_bits, m0, m1, m2), m_c = cand ? 0xFFFFFFFF : 0.
// ---------------------------------------------------------------------------
__global__ void __launch_bounds__(256) prep_kernel(
    const float* __restrict__ pre_score, const float* __restrict__ rois,
    uint4* __restrict__ mrec)
{
    int b = blockIdx.x;
    int tid = threadIdx.x;
    __shared__ float sv[256];
    __shared__ int   si[256];
    __shared__ int   sc[256];

    float v0[8], v1[8], v2[8];
    unsigned char bits[8];
#pragma unroll
    for (int t = 0; t < 8; ++t) {
        int j = t * 256 + tid;
        const float* p = pre_score + ((size_t)b * PP + j) * 3;
        v0[t] = p[0]; v1[t] = p[1]; v2[t] = p[2];
        bits[t] = 0;
    }

#define PREP_CLASS(VV, CBIT)                                                   \
    {                                                                          \
        float bv = -1.0f; int bi = 0; int cnt = 0;                             \
        _Pragma("unroll")                                                      \
        for (int t = 0; t < 8; ++t) {                                          \
            int j = t * 256 + tid;                                             \
            float v = VV[t];                                                   \
            if (v > 0.5f) cnt++;                                               \
            if (v > bv) { bv = v; bi = j; }                                    \
        }                                                                      \
        sv[tid] = bv; si[tid] = bi; sc[tid] = cnt;                             \
        __syncthreads();                                                       \
        for (int s2 = 128; s2 > 0; s2 >>= 1) {                                 \
            if (tid < s2) {                                                    \
                float ov = sv[tid + s2]; int oi = si[tid + s2];                \
                if (ov > sv[tid] || (ov == sv[tid] && oi < si[tid])) {         \
                    sv[tid] = ov; si[tid] = oi;                                \
                }                                                              \
                sc[tid] += sc[tid + s2];                                       \
            }                                                                  \
            __syncthreads();                                                   \
        }                                                                      \
        int total = sc[0];                                                     \
        int amax  = si[0];                                                     \
        __syncthreads();                                                       \
        _Pragma("unroll")                                                      \
        for (int t = 0; t < 8; ++t) {                                          \
            int j = t * 256 + tid;                                             \
            bool cb = (total <= 1) ? (j == amax) : (VV[t] > 0.5f);             \
            if (cb) bits[t] |= (unsigned char)(CBIT);                          \
        }                                                                      \
    }

    PREP_CLASS(v0, 1)
    PREP_CLASS(v1, 2)
    PREP_CLASS(v2, 4)
#undef PREP_CLASS

    const float4* rb = (const float4*)(rois + (size_t)b * PP * 4);
#pragma unroll
    for (int t = 0; t < 8; ++t) {
        int j = t * 256 + tid;
        float4 bx = rb[j];
        float area = (bx.z - bx.x) * (bx.w - bx.y);
        uint4 r;
        r.x = __float_as_uint(area);
        r.y = (bits[t] & 1) ? 0xFFFFFFFFu : 0u;
        r.z = (bits[t] & 2) ? 0xFFFFFFFFu : 0u;
        r.w = (bits[t] & 4) ? 0xFFFFFFFFu : 0u;
        mrec[(size_t)b * PP + j] = r;
    }
}

// ---------------------------------------------------------------------------
// K3: iou — block = 512 thr (8 waves) covers 256 i's (4 slots/lane) x 256 j's.
// Packed-key argmax: key = (iou_bits & HIMASK) | (2047 - j_global), masked per
// class by AND with all-ones/zero mask; running v_max_u32. Keys are globally
// unique per j => any max order preserves exact first-max tie-break.
// ---------------------------------------------------------------------------
__global__ void __launch_bounds__(512) iou_kernel(
    const float* __restrict__ rois, const uint4* __restrict__ mrec,
    unsigned* __restrict__ qres)
{
    __shared__ float4   boxesL[JQ];       // 4 KiB
    __shared__ uint4    mrecL[JQ];        // 4 KiB
    __shared__ unsigned bestA[3][8][IT];  // 24 KiB
    int bid = blockIdx.x;
    int q   = bid & 7;
    int it  = (bid >> 3) & 7;
    int b   = bid >> 6;
    int tid = threadIdx.x;

    const float4* rbase = (const float4*)(rois + (size_t)b * PP * 4);
    if (tid < JQ) boxesL[tid] = rbase[q * JQ + tid];
    else          mrecL[tid - JQ] = mrec[(size_t)b * PP + q * JQ + (tid - JQ)];
    __syncthreads();

    int lane = tid & 63, w = tid >> 6;
    float4 bx[4];
    float  ax[4];
#pragma unroll
    for (int s = 0; s < 4; ++s) {
        bx[s] = rbase[it * IT + s * 64 + lane];
        ax[s] = (bx[s].z - bx[s].x) * (bx[s].w - bx[s].y);
    }

    int jb = w * 32;                       // local j base for this wave
    int jfbase = 2047 - q * JQ - jb;       // scalar

    unsigned best[4][3];
#pragma unroll
    for (int s = 0; s < 4; ++s) {
        best[s][0] = 0u; best[s][1] = 0u; best[s][2] = 0u;
    }

#pragma unroll 4
    for (int jj = 0; jj < 32; ++jj) {
        float4 bj = boxesL[jb + jj];
        uint4  mj = mrecL[jb + jj];
        float  aj = __uint_as_float(mj.x);
        unsigned jf = (unsigned)(jfbase - jj);
#pragma unroll
        for (int s = 0; s < 4; ++s) {
            float lx = fmaxf(bx[s].x, bj.x), ly = fmaxf(bx[s].y, bj.y);
            float rx = fminf(bx[s].z, bj.z), ry = fminf(bx[s].w, bj.w);
            float ww = fmaxf(rx - lx, 0.f), hh = fmaxf(ry - ly, 0.f);
            float inter = ww * hh;
            float uni   = ax[s] + aj - inter;
            float iou   = inter * __builtin_amdgcn_rcpf(uni);
            unsigned pk = (__float_as_uint(iou) & HIMASK) | jf;
            unsigned k0 = pk & mj.y, k1 = pk & mj.z, k2 = pk & mj.w;
            best[s][0] = best[s][0] > k0 ? best[s][0] : k0;
            best[s][1] = best[s][1] > k1 ? best[s][1] : k1;
            best[s][2] = best[s][2] > k2 ? best[s][2] : k2;
        }
    }
#pragma unroll
    for (int s = 0; s < 4; ++s) {
        bestA[0][w][s * 64 + lane] = best[s][0];
        bestA[1][w][s * 64 + lane] = best[s][1];
        bestA[2][w][s * 64 + lane] = best[s][2];
    }
    __syncthreads();

    if (tid < IT) {
#pragma unroll
        for (int c = 0; c < 3; ++c) {
            unsigned m = bestA[c][0][tid];
#pragma unroll
            for (int w2 = 1; w2 < 8; ++w2) {
                unsigned o = bestA[c][w2][tid];
                m = m > o ? m : o;
            }
            qres[(((size_t)b * NQ + q) * 3 + c) * PP + it * IT + tid] = m;
        }
    }
}

// ---------------------------------------------------------------------------
// K4: merge j-slices + sequential class logic + focal loss; per-(b,it)
// partial sums. 128 blocks x 256 threads.
// ---------------------------------------------------------------------------
__global__ void __launch_bounds__(256) merge_focal_kernel(
    const unsigned* __restrict__ qres, const float* __restrict__ pre_score,
    const int* __restrict__ labels, const float* __restrict__ xr,
    float* __restrict__ partials)
{
    __shared__ float redw[4], redf[4];
    int bt = blockIdx.x;
    int b = bt >> 3, it = bt & 7;
    int tid = threadIdx.x;   // 0..255
    int i = it * IT + tid;

    float I = 0.f, wv = 0.f;
    int target = 3;
#pragma unroll
    for (int c = 0; c < 3; ++c) {
        unsigned k = 0u;
#pragma unroll
        for (int qq = 0; qq < NQ; ++qq) {
            unsigned h = qres[(((size_t)b * NQ + qq) * 3 + c) * PP + i];
            k = k > h ? k : h;   // packed keys globally unique per j
        }
        int   jv    = 2047 - (int)(k & 2047u);
        float bestv = __uint_as_float(k & HIMASK);
        bestv = (labels[b * 3 + c] != 0) ? bestv : -1.0f;
        if (bestv > I) {
            wv = pre_score[((size_t)b * PP + jv) * 3 + c];
            if (bestv > 0.5f && target == 3) target = c;
            I = bestv;
        }
    }
    // focal loss on double-softmaxed scores
    int gi = b * PP + i;
    float4 x4 = ((const float4*)xr)[gi];
    float m = fmaxf(fmaxf(x4.x, x4.y), fmaxf(x4.z, x4.w));
    float e0 = expf(x4.x - m), e1 = expf(x4.y - m), e2 = expf(x4.z - m), e3 = expf(x4.w - m);
    float ssum = e0 + e1 + e2 + e3;
    float et = (target == 0) ? e0 : (target == 1) ? e1 : (target == 2) ? e2 : e3;
    float pt = et / ssum;
    pt = fminf(fmaxf(pt, 1e-7f), 1.0f - 1e-7f);
    float fl = -logf(pt) * (1.0f - pt) * (1.0f - pt);

    float sw = wv, sf = fl;
#pragma unroll
    for (int off = 32; off > 0; off >>= 1) {
        sw += __shfl_down(sw, off);
        sf += __shfl_down(sf, off);
    }
    if ((tid & 63) == 0) { redw[tid >> 6] = sw; redf[tid >> 6] = sf; }
    __syncthreads();
    if (tid == 0) {
        partials[bt * 2 + 0] = redw[0] + redw[1] + redw[2] + redw[3];
        partials[bt * 2 + 1] = redf[0] + redf[1] + redf[2] + redf[3];
    }
}

// ---------------------------------------------------------------------------
// K5: deterministic finalize: loss = mean(w) * mean(floss)
// ---------------------------------------------------------------------------
__global__ void __launch_bounds__(256) finalize_kernel(
    const float* __restrict__ partials, float* __restrict__ out_loss)
{
    __shared__ float swL[256], sfL[256];
    int tid = threadIdx.x;
    float sw = (tid < NBT2) ? partials[2 * tid] : 0.f;
    float sf = (tid < NBT2) ? partials[2 * tid + 1] : 0.f;
    swL[tid] = sw; sfL[tid] = sf;
    __syncthreads();
    for (int s = 128; s > 0; s >>= 1) {
        if (tid < s) { swL[tid] += swL[tid + s]; sfL[tid] += sfL[tid + s]; }
        __syncthreads();
    }
    if (tid == 0)
        out_loss[0] = (swL[0] / (float)NROW) * (sfL[0] / (float)NROW);
}

// ---------------------------------------------------------------------------
extern "C" void kernel_launch(void* const* d_in, const int* in_sizes, int n_in,
                              void* d_out, int out_size, void* d_ws, size_t ws_size,
                              hipStream_t stream)
{
    const float* inputs    = (const float*)d_in[0];
    const float* pre_score = (const float*)d_in[1];
    const int*   labels    = (const int*)d_in[2];
    const float* rois      = (const float*)d_in[3];
    // d_in[4] = num (2048, fixed)
    const float* fc_w      = (const float*)d_in[5];
    const float* fc_b      = (const float*)d_in[6];

    float* out = (float*)d_out;
    unsigned* qres = (unsigned*)d_ws;                                  // 3.0 MiB
    uint4* mrec = (uint4*)((char*)d_ws
                 + (size_t)BS * NQ * 3 * PP * sizeof(unsigned));       // 512 KiB
    float* partials = (float*)((char*)mrec + (size_t)BS * PP * sizeof(uint4));

    prep_kernel<<<BS, 256, 0, stream>>>(pre_score, rois, mrec);
    fc_softmax_kernel<<<NROW / 16, 256, 0, stream>>>(inputs, fc_w, fc_b, out);
    iou_kernel<<<NBLK_IOU, 512, 0, stream>>>(rois, mrec, qres);
    merge_focal_kernel<<<NBT2, 256, 0, stream>>>(qres, pre_score, labels, out, partials);
    finalize_kernel<<<1, 256, 0, stream>>>(partials, out + (size_t)NROW * 4);
}